// Round 4
// baseline (468.089 us; speedup 1.0000x reference)
//
#include <hip/hip_runtime.h>
#include <hip/hip_bf16.h>

typedef __bf16 bf16x8 __attribute__((ext_vector_type(8)));
typedef float  f32x4  __attribute__((ext_vector_type(4)));

#define B_ROWS 65536
#define KC1 22           // 704/32
#define KC2 8
#define KC3 4
#define H1S 264          // h1 LDS stride (256+8 pad)
#define H2S 136          // h2 LDS stride (128+8 pad)

#define W1B_ELEMS (704*256)
#define W2B_ELEMS (256*128)
#define W3B_ELEMS (128*16)
#define WPACK_BYTES ((size_t)(W1B_ELEMS + W2B_ELEMS + W3B_ELEMS) * 2)
#define H0B_BYTES ((size_t)B_ROWS * 704 * 2)

// ---------------- weight pack: bf16 MFMA-B layout [kc][n][ki(32)] ----------
__global__ void pack_weights(const float* __restrict__ w1,
                             const float* __restrict__ w2,
                             const float* __restrict__ w3,
                             __hip_bfloat16* __restrict__ w1b,
                             __hip_bfloat16* __restrict__ w2b,
                             __hip_bfloat16* __restrict__ w3b) {
    int idx = blockIdx.x * 256 + threadIdx.x;
    if (idx < W1B_ELEMS) {
        int ki = idx & 31, t = idx >> 5;
        int n = t & 255, kc = t >> 8;
        int k = kc * 32 + ki;
        float v = (k < 676) ? w1[k * 256 + n] : 0.0f;
        w1b[idx] = __float2bfloat16(v);
    } else if (idx < W1B_ELEMS + W2B_ELEMS) {
        int j = idx - W1B_ELEMS;
        int ki = j & 31, t = j >> 5;
        int n = t & 127, kc = t >> 7;
        w2b[j] = __float2bfloat16(w2[(kc * 32 + ki) * 128 + n]);
    } else if (idx < W1B_ELEMS + W2B_ELEMS + W3B_ELEMS) {
        int j = idx - W1B_ELEMS - W2B_ELEMS;
        int ki = j & 31, t = j >> 5;
        int n = t & 15, kc = t >> 4;
        float v = (n < 10) ? w3[(kc * 32 + ki) * 10 + n] : 0.0f;
        w3b[j] = __float2bfloat16(v);
    }
}

// ---------------- conv kernel: x -> h0b in MFMA-A fragment order -----------
// h0b elem index: ((r>>4)*22 + kc)*512 + (r&15)*32 + ki,  k = kc*32+ki.
// Task t = r*27 + i:  i<26 -> conv output row i (26 values, fp32 exact);
//                     i==26 -> zero-pad k=676..703.
// No LDS, no barriers: pure streaming, latency hidden by TLP.
__global__ __launch_bounds__(256, 2)
void conv_kernel(const float* __restrict__ x, const float* __restrict__ cw,
                 __hip_bfloat16* __restrict__ h0b) {
    int t = blockIdx.x * 256 + threadIdx.x;
    int r = t / 27;
    int i = t - r * 27;
    __hip_bfloat16* base = h0b + ((size_t)(r >> 4) * 22) * 512 + (r & 15) * 32;

    if (i == 26) {  // zero k=676..703: kc=21, ki 4..31 -> 14 aligned 4B stores
        unsigned int* p = (unsigned int*)(base + (size_t)21 * 512 + 4);
        #pragma unroll
        for (int q = 0; q < 14; q++) p[q] = 0u;
        return;
    }

    const float c00 = cw[0], c01 = cw[1], c02 = cw[2];
    const float c10 = cw[3], c11 = cw[4], c12 = cw[5];
    const float c20 = cw[6], c21 = cw[7], c22 = cw[8];

    // 3 input rows = 84 contiguous floats, 21 float4 loads issued up front.
    const float4* p4 = (const float4*)(x + (size_t)r * 784 + i * 28);
    union { float4 v4[21]; float f[84]; } u;
    #pragma unroll
    for (int q = 0; q < 21; q++) u.v4[q] = p4[q];

    #pragma unroll
    for (int j = 0; j < 26; j += 2) {
        float a0 = c00*u.f[j]    + c01*u.f[j+1]  + c02*u.f[j+2]
                 + c10*u.f[28+j] + c11*u.f[29+j] + c12*u.f[30+j]
                 + c20*u.f[56+j] + c21*u.f[57+j] + c22*u.f[58+j];
        float a1 = c00*u.f[j+1]  + c01*u.f[j+2]  + c02*u.f[j+3]
                 + c10*u.f[29+j] + c11*u.f[30+j] + c12*u.f[31+j]
                 + c20*u.f[57+j] + c21*u.f[58+j] + c22*u.f[59+j];
        int k = i * 26 + j;                       // even -> 4B-aligned pair
        __hip_bfloat162 pv;
        pv.x = __float2bfloat16(a0);
        pv.y = __float2bfloat16(a1);
        *(__hip_bfloat162*)(base + (size_t)(k >> 5) * 512 + (k & 31)) = pv;
    }
}

// ---------------- gemm kernel: h0b -> out ----------------------------------
// MR=32 rows/block, 256 threads. GEMM1 A-frags read DIRECTLY from global
// (fragment-order h0b) -> no conv barrier, no big LDS; LDS only h1+h2
// (25.6 KB) -> 4+ blocks/CU.
__global__ __launch_bounds__(256, 4)
void gemm_kernel(const __hip_bfloat16* __restrict__ h0b,
                 const __hip_bfloat16* __restrict__ w1b, const float* __restrict__ b1,
                 const __hip_bfloat16* __restrict__ w2b, const float* __restrict__ b2,
                 const __hip_bfloat16* __restrict__ w3b, const float* __restrict__ b3,
                 float* __restrict__ out) {
    __shared__ __align__(16) __hip_bfloat16 h1s[32 * H1S];
    __shared__ __align__(16) __hip_bfloat16 h2s[32 * H2S];

    const int tid  = threadIdx.x;
    const int wave = tid >> 6;
    const int lane = tid & 63;
    const int l15  = lane & 15;
    const int g    = lane >> 4;
    const int r0   = blockIdx.x * 32;
    const int rgA  = blockIdx.x * 2;          // two 16-row A groups

    // ---- GEMM1: h1 = relu(h0 @ w1 + b1), M=32 N=256 K=704 ----
    {
        const __hip_bfloat16* a0p = h0b + ((size_t)(rgA + 0) * 22) * 512 + l15 * 32 + g * 8;
        const __hip_bfloat16* a1p = h0b + ((size_t)(rgA + 1) * 22) * 512 + l15 * 32 + g * 8;
        const int nb = wave * 64;
        const __hip_bfloat16* bbase = w1b + ((size_t)(nb + l15) * 32 + g * 8);

        f32x4 acc[2][4];
        #pragma unroll
        for (int mt = 0; mt < 2; mt++)
            #pragma unroll
            for (int nt = 0; nt < 4; nt++)
                acc[mt][nt] = (f32x4){0.f, 0.f, 0.f, 0.f};

        bf16x8 bcur[4], acur[2];
        #pragma unroll
        for (int nt = 0; nt < 4; nt++)
            bcur[nt] = *(const bf16x8*)(bbase + nt * 512);
        acur[0] = *(const bf16x8*)(a0p);
        acur[1] = *(const bf16x8*)(a1p);

        for (int kc = 0; kc < KC1; kc++) {
            bf16x8 bnext[4], anext[2];
            if (kc + 1 < KC1) {
                const __hip_bfloat16* bp = bbase + (size_t)(kc + 1) * 8192;
                #pragma unroll
                for (int nt = 0; nt < 4; nt++)
                    bnext[nt] = *(const bf16x8*)(bp + nt * 512);
                anext[0] = *(const bf16x8*)(a0p + (size_t)(kc + 1) * 512);
                anext[1] = *(const bf16x8*)(a1p + (size_t)(kc + 1) * 512);
            }
            #pragma unroll
            for (int mt = 0; mt < 2; mt++)
                #pragma unroll
                for (int nt = 0; nt < 4; nt++)
                    acc[mt][nt] = __builtin_amdgcn_mfma_f32_16x16x32_bf16(
                        acur[mt], bcur[nt], acc[mt][nt], 0, 0, 0);
            if (kc + 1 < KC1) {
                #pragma unroll
                for (int nt = 0; nt < 4; nt++) bcur[nt] = bnext[nt];
                acur[0] = anext[0];
                acur[1] = anext[1];
            }
        }
        #pragma unroll
        for (int nt = 0; nt < 4; nt++) {
            const int n = nb + nt * 16 + l15;
            const float bias = b1[n];
            #pragma unroll
            for (int mt = 0; mt < 2; mt++) {
                #pragma unroll
                for (int q = 0; q < 4; q++) {
                    const int row = mt * 16 + g * 4 + q;   // col=lane&15, row=(lane>>4)*4+q
                    float v = acc[mt][nt][q] + bias;
                    h1s[row * H1S + n] = __float2bfloat16(fmaxf(v, 0.0f));
                }
            }
        }
    }
    __syncthreads();

    // ---- GEMM2: h2 = relu(h1 @ w2 + b2), M=32 N=128 K=256 ----
    {
        f32x4 acc[2][2];
        #pragma unroll
        for (int mt = 0; mt < 2; mt++)
            #pragma unroll
            for (int nt = 0; nt < 2; nt++)
                acc[mt][nt] = (f32x4){0.f, 0.f, 0.f, 0.f};
        const int nb = wave * 32;
        #pragma unroll
        for (int kc = 0; kc < KC2; kc++) {
            bf16x8 a[2], b[2];
            #pragma unroll
            for (int mt = 0; mt < 2; mt++)
                a[mt] = *(const bf16x8*)(h1s + (mt * 16 + l15) * H1S + kc * 32 + g * 8);
            #pragma unroll
            for (int nt = 0; nt < 2; nt++)
                b[nt] = *(const bf16x8*)(w2b + (((size_t)kc * 128 + nb + nt * 16 + l15) * 32 + g * 8));
            #pragma unroll
            for (int mt = 0; mt < 2; mt++)
                #pragma unroll
                for (int nt = 0; nt < 2; nt++)
                    acc[mt][nt] = __builtin_amdgcn_mfma_f32_16x16x32_bf16(
                        a[mt], b[nt], acc[mt][nt], 0, 0, 0);
        }
        #pragma unroll
        for (int nt = 0; nt < 2; nt++) {
            const int n = nb + nt * 16 + l15;
            const float bias = b2[n];
            #pragma unroll
            for (int mt = 0; mt < 2; mt++) {
                #pragma unroll
                for (int q = 0; q < 4; q++) {
                    const int row = mt * 16 + g * 4 + q;
                    float v = acc[mt][nt][q] + bias;
                    h2s[row * H2S + n] = __float2bfloat16(fmaxf(v, 0.0f));
                }
            }
        }
    }
    __syncthreads();

    // ---- GEMM3: out = h2 @ w3 + b3, M=32 N=16(10) K=128 ----
    if (wave < 2) {
        f32x4 acc3 = (f32x4){0.f, 0.f, 0.f, 0.f};
        #pragma unroll
        for (int kc = 0; kc < KC3; kc++) {
            bf16x8 a = *(const bf16x8*)(h2s + (wave * 16 + l15) * H2S + kc * 32 + g * 8);
            bf16x8 b = *(const bf16x8*)(w3b + (((size_t)kc * 16 + l15) * 32 + g * 8));
            acc3 = __builtin_amdgcn_mfma_f32_16x16x32_bf16(a, b, acc3, 0, 0, 0);
        }
        if (l15 < 10) {
            const float bias = b3[l15];
            #pragma unroll
            for (int q = 0; q < 4; q++) {
                const int row = wave * 16 + g * 4 + q;
                out[(size_t)(r0 + row) * 10 + l15] = acc3[q] + bias;
            }
        }
    }
}

// ---------------- fallback fused kernel (if ws_size too small) -------------
#define FMR 16
#define FH0S 712
__global__ __launch_bounds__(256, 4)
void fused_model(const float* __restrict__ x, const float* __restrict__ cw,
                 const __hip_bfloat16* __restrict__ w1b, const float* __restrict__ b1,
                 const __hip_bfloat16* __restrict__ w2b, const float* __restrict__ b2,
                 const __hip_bfloat16* __restrict__ w3b, const float* __restrict__ b3,
                 float* __restrict__ out) {
    __shared__ __align__(16) char smem[FMR * FH0S * 2 + FMR * H1S * 2];
    __hip_bfloat16* h0s = (__hip_bfloat16*)smem;
    __hip_bfloat16* h1s = (__hip_bfloat16*)(smem + FMR * FH0S * 2);
    __hip_bfloat16* h2s = (__hip_bfloat16*)smem;
    const int tid = threadIdx.x;
    const int r0  = blockIdx.x * FMR;
    const float c00 = cw[0], c01 = cw[1], c02 = cw[2];
    const float c10 = cw[3], c11 = cw[4], c12 = cw[5];
    const float c20 = cw[6], c21 = cw[7], c22 = cw[8];
    for (int t = tid; t < FMR * 52; t += 256) {
        int r = t / 52, q = t - r * 52, i = q >> 1, j0 = (q & 1) * 13;
        int s = j0 ? 12 : 0;
        union { float4 v4[12]; float f[48]; } u;
        #pragma unroll
        for (int di = 0; di < 3; di++) {
            const float4* p = (const float4*)(x + (size_t)(r0 + r) * 784 + (i + di) * 28 + s);
            u.v4[di*4+0] = p[0]; u.v4[di*4+1] = p[1]; u.v4[di*4+2] = p[2]; u.v4[di*4+3] = p[3];
        }
        const int o = j0 ? 1 : 0;
        __hip_bfloat16* hp = h0s + r * FH0S + i * 26 + j0;
        #pragma unroll
        for (int jj = 0; jj < 13; jj++) {
            const int b = jj + o;
            float a = c00*u.f[b] + c01*u.f[b+1] + c02*u.f[b+2]
                    + c10*u.f[16+b] + c11*u.f[17+b] + c12*u.f[18+b]
                    + c20*u.f[32+b] + c21*u.f[33+b] + c22*u.f[34+b];
            hp[jj] = __float2bfloat16(a);
        }
    }
    for (int t = tid; t < FMR * 28; t += 256) {
        int r = t / 28, c = 676 + (t - r * 28);
        h0s[r * FH0S + c] = __float2bfloat16(0.0f);
    }
    const int wave = tid >> 6, lane = tid & 63, l15 = lane & 15, g = lane >> 4;
    {
        const int nb = wave * 64;
        const __hip_bfloat16* bbase = w1b + ((size_t)(nb + l15) * 32 + g * 8);
        bf16x8 bcur[4];
        #pragma unroll
        for (int nt = 0; nt < 4; nt++) bcur[nt] = *(const bf16x8*)(bbase + nt * 512);
        __syncthreads();
        f32x4 acc[4];
        #pragma unroll
        for (int nt = 0; nt < 4; nt++) acc[nt] = (f32x4){0.f,0.f,0.f,0.f};
        bf16x8 acur = *(const bf16x8*)(h0s + l15 * FH0S + g * 8);
        for (int kc = 0; kc < KC1; kc++) {
            bf16x8 bnext[4], anext;
            if (kc + 1 < KC1) {
                const __hip_bfloat16* bp = bbase + (size_t)(kc + 1) * 8192;
                #pragma unroll
                for (int nt = 0; nt < 4; nt++) bnext[nt] = *(const bf16x8*)(bp + nt * 512);
                anext = *(const bf16x8*)(h0s + l15 * FH0S + (kc + 1) * 32 + g * 8);
            }
            #pragma unroll
            for (int nt = 0; nt < 4; nt++)
                acc[nt] = __builtin_amdgcn_mfma_f32_16x16x32_bf16(acur, bcur[nt], acc[nt], 0, 0, 0);
            if (kc + 1 < KC1) {
                #pragma unroll
                for (int nt = 0; nt < 4; nt++) bcur[nt] = bnext[nt];
                acur = anext;
            }
        }
        #pragma unroll
        for (int nt = 0; nt < 4; nt++) {
            const int n = nb + nt * 16 + l15;
            const float bias = b1[n];
            #pragma unroll
            for (int q = 0; q < 4; q++)
                h1s[(g*4+q) * H1S + n] = __float2bfloat16(fmaxf(acc[nt][q] + bias, 0.0f));
        }
    }
    __syncthreads();
    {
        f32x4 acc[2];
        acc[0] = (f32x4){0.f,0.f,0.f,0.f}; acc[1] = (f32x4){0.f,0.f,0.f,0.f};
        const int nb = wave * 32;
        #pragma unroll
        for (int kc = 0; kc < KC2; kc++) {
            bf16x8 a  = *(const bf16x8*)(h1s + l15 * H1S + kc * 32 + g * 8);
            bf16x8 b0 = *(const bf16x8*)(w2b + (((size_t)kc * 128 + nb + l15) * 32 + g * 8));
            bf16x8 b1v= *(const bf16x8*)(w2b + (((size_t)kc * 128 + nb + 16 + l15) * 32 + g * 8));
            acc[0] = __builtin_amdgcn_mfma_f32_16x16x32_bf16(a, b0, acc[0], 0, 0, 0);
            acc[1] = __builtin_amdgcn_mfma_f32_16x16x32_bf16(a, b1v, acc[1], 0, 0, 0);
        }
        #pragma unroll
        for (int nt = 0; nt < 2; nt++) {
            const int n = nb + nt * 16 + l15;
            const float bias = b2[n];
            #pragma unroll
            for (int q = 0; q < 4; q++)
                h2s[(g*4+q) * H2S + n] = __float2bfloat16(fmaxf(acc[nt][q] + bias, 0.0f));
        }
    }
    __syncthreads();
    if (wave == 0) {
        f32x4 acc3 = (f32x4){0.f,0.f,0.f,0.f};
        #pragma unroll
        for (int kc = 0; kc < KC3; kc++) {
            bf16x8 a = *(const bf16x8*)(h2s + l15 * H2S + kc * 32 + g * 8);
            bf16x8 b = *(const bf16x8*)(w3b + (((size_t)kc * 16 + l15) * 32 + g * 8));
            acc3 = __builtin_amdgcn_mfma_f32_16x16x32_bf16(a, b, acc3, 0, 0, 0);
        }
        if (l15 < 10) {
            const float bias = b3[l15];
            #pragma unroll
            for (int q = 0; q < 4; q++)
                out[(size_t)(r0 + g*4 + q) * 10 + l15] = acc3[q] + bias;
        }
    }
}

extern "C" void kernel_launch(void* const* d_in, const int* in_sizes, int n_in,
                              void* d_out, int out_size, void* d_ws, size_t ws_size,
                              hipStream_t stream) {
    const float* x  = (const float*)d_in[0];
    const float* cw = (const float*)d_in[1];
    const float* w1 = (const float*)d_in[2];
    const float* b1 = (const float*)d_in[3];
    const float* w2 = (const float*)d_in[4];
    const float* b2 = (const float*)d_in[5];
    const float* w3 = (const float*)d_in[6];
    const float* b3 = (const float*)d_in[7];
    float* out = (float*)d_out;

    __hip_bfloat16* w1b = (__hip_bfloat16*)d_ws;
    __hip_bfloat16* w2b = w1b + W1B_ELEMS;
    __hip_bfloat16* w3b = w2b + W2B_ELEMS;

    const int pack_total = W1B_ELEMS + W2B_ELEMS + W3B_ELEMS;  // 215040
    pack_weights<<<(pack_total + 255) / 256, 256, 0, stream>>>(w1, w2, w3, w1b, w2b, w3b);

    if (ws_size >= WPACK_BYTES + H0B_BYTES) {
        __hip_bfloat16* h0b = (__hip_bfloat16*)((char*)d_ws + WPACK_BYTES);
        conv_kernel<<<(B_ROWS * 27) / 256, 256, 0, stream>>>(x, cw, h0b);
        gemm_kernel<<<B_ROWS / 32, 256, 0, stream>>>(h0b, w1b, b1, w2b, b2, w3b, b3, out);
    } else {
        fused_model<<<B_ROWS / FMR, 256, 0, stream>>>(x, cw, w1b, b1, w2b, b2, w3b, b3, out);
    }
}

// Round 6
// 376.798 us; speedup vs baseline: 1.2423x; 1.2423x over previous
//
#include <hip/hip_runtime.h>
#include <hip/hip_bf16.h>

typedef __bf16 bf16x8 __attribute__((ext_vector_type(8)));
typedef float  f32x4  __attribute__((ext_vector_type(4)));

#define B_ROWS 65536
#define KC1 22           // 704/32
#define KC2 8
#define KC3 4
#define H1S 264          // h1 LDS stride (256+8 pad)
#define H2S 136          // h2 LDS stride (128+8 pad)

#define W1B_ELEMS (704*256)
#define W2B_ELEMS (256*128)
#define W3B_ELEMS (128*16)
#define WPACK_BYTES ((size_t)(W1B_ELEMS + W2B_ELEMS + W3B_ELEMS) * 2)
#define H0B_BYTES ((size_t)B_ROWS * 704 * 2)

// ---------------- weight pack: bf16 MFMA-B layout [kc][n][ki(32)] ----------
__global__ void pack_weights(const float* __restrict__ w1,
                             const float* __restrict__ w2,
                             const float* __restrict__ w3,
                             __hip_bfloat16* __restrict__ w1b,
                             __hip_bfloat16* __restrict__ w2b,
                             __hip_bfloat16* __restrict__ w3b) {
    int idx = blockIdx.x * 256 + threadIdx.x;
    if (idx < W1B_ELEMS) {
        int ki = idx & 31, t = idx >> 5;
        int n = t & 255, kc = t >> 8;
        int k = kc * 32 + ki;
        float v = (k < 676) ? w1[k * 256 + n] : 0.0f;
        w1b[idx] = __float2bfloat16(v);
    } else if (idx < W1B_ELEMS + W2B_ELEMS) {
        int j = idx - W1B_ELEMS;
        int ki = j & 31, t = j >> 5;
        int n = t & 127, kc = t >> 7;
        w2b[j] = __float2bfloat16(w2[(kc * 32 + ki) * 128 + n]);
    } else if (idx < W1B_ELEMS + W2B_ELEMS + W3B_ELEMS) {
        int j = idx - W1B_ELEMS - W2B_ELEMS;
        int ki = j & 31, t = j >> 5;
        int n = t & 15, kc = t >> 4;
        float v = (n < 10) ? w3[(kc * 32 + ki) * 10 + n] : 0.0f;
        w3b[j] = __float2bfloat16(v);
    }
}

// ---------------- conv kernel v2: LDS-staged, coalesced both ways ----------
// h0b elem index: ((r>>4)*22 + kc)*512 + (r&15)*32 + ki,  k = kc*32+ki.
// Block = 8 images. Stage A: coalesced global->LDS (8*784 floats, named
// float4 temps -> SROA-safe, stays in VGPRs). Stage B: conv from LDS (cheap
// ds_read latency), scatter bf16 into LDS h0-tile [kc][m(8)][ki(32)].
// Stage C: coalesced 16B copy LDS->global. NO unions anywhere (unions defeat
// SROA -> scratch spill: R2-R4's VGPR=32..48 + inflated WRITE_SIZE).
#define CG 8
__global__ __launch_bounds__(256, 4)
void conv_kernel(const float* __restrict__ x, const float* __restrict__ cw,
                 __hip_bfloat16* __restrict__ h0b) {
    __shared__ __align__(16) float xs[CG * 784];            // 25088 B
    __shared__ __align__(16) __hip_bfloat16 h0t[CG * 704];  // 11264 B
    const int tid = threadIdx.x;
    const int r0  = blockIdx.x * CG;

    const float c00 = cw[0], c01 = cw[1], c02 = cw[2];
    const float c10 = cw[3], c11 = cw[4], c12 = cw[5];
    const float c20 = cw[6], c21 = cw[7], c22 = cw[8];

    // ---- Stage A: 8 contiguous images = 1568 float4, coalesced ----
    {
        const float4* gx = (const float4*)(x + (size_t)r0 * 784);
        float4* xs4 = (float4*)xs;
        float4 t0 = gx[tid];
        float4 t1 = gx[tid + 256];
        float4 t2 = gx[tid + 512];
        float4 t3 = gx[tid + 768];
        float4 t4 = gx[tid + 1024];
        float4 t5 = gx[tid + 1280];
        float4 t6;
        if (tid < 32) t6 = gx[tid + 1536];
        xs4[tid]        = t0;
        xs4[tid + 256]  = t1;
        xs4[tid + 512]  = t2;
        xs4[tid + 768]  = t3;
        xs4[tid + 1024] = t4;
        xs4[tid + 1280] = t5;
        if (tid < 32) xs4[tid + 1536] = t6;
    }
    __syncthreads();

    // ---- Stage B: conv fp32, 8 img x 26 rows = 208 tasks ----
    if (tid < CG * 26) {
        const int m = tid / 26;          // image in group
        const int i = tid - m * 26;      // output row
        const float* xr = xs + m * 784 + i * 28;
        float rb[84];                     // plain array, const indices -> SROA
        #pragma unroll
        for (int q = 0; q < 21; q++) {
            float4 v = *(const float4*)(xr + q * 4);
            rb[q*4+0] = v.x; rb[q*4+1] = v.y; rb[q*4+2] = v.z; rb[q*4+3] = v.w;
        }
        #pragma unroll
        for (int j = 0; j < 26; j += 2) {
            float a0 = c00*rb[j]    + c01*rb[j+1]  + c02*rb[j+2]
                     + c10*rb[28+j] + c11*rb[29+j] + c12*rb[30+j]
                     + c20*rb[56+j] + c21*rb[57+j] + c22*rb[58+j];
            float a1 = c00*rb[j+1]  + c01*rb[j+2]  + c02*rb[j+3]
                     + c10*rb[29+j] + c11*rb[30+j] + c12*rb[31+j]
                     + c20*rb[57+j] + c21*rb[58+j] + c22*rb[59+j];
            const int k = i * 26 + j;    // even; pair stays inside a 32-chunk
            __hip_bfloat162 pv;
            pv.x = __float2bfloat16(a0);
            pv.y = __float2bfloat16(a1);
            *(__hip_bfloat162*)(h0t + (k >> 5) * (CG * 32) + m * 32 + (k & 31)) = pv;
        }
    }
    // zero-pad k = 676..703 (kc=21, ki 4..31) for all 8 images: 224 elems
    for (int u = tid; u < CG * 28; u += 256) {
        int m = u / 28, ki = 4 + (u - m * 28);
        h0t[21 * (CG * 32) + m * 32 + ki] = __float2bfloat16(0.0f);
    }
    __syncthreads();

    // ---- Stage C: coalesced LDS->global, 704 x 16B units ----
    // group (r0>>4), half = (r0>>3)&1 selects rows 0-7 / 8-15 of the group.
    __hip_bfloat16* gout = h0b + ((size_t)(r0 >> 4) * 22) * 512 + ((r0 >> 3) & 1) * 256;
    for (int u = tid; u < 704; u += 256) {
        bf16x8 v = *(const bf16x8*)(h0t + u * 8);
        *(bf16x8*)(gout + (size_t)(u >> 5) * 512 + (u & 31) * 8) = v;
    }
}

// ---------------- gemm kernel: h0b -> out (unchanged from round 4) ---------
__global__ __launch_bounds__(256, 4)
void gemm_kernel(const __hip_bfloat16* __restrict__ h0b,
                 const __hip_bfloat16* __restrict__ w1b, const float* __restrict__ b1,
                 const __hip_bfloat16* __restrict__ w2b, const float* __restrict__ b2,
                 const __hip_bfloat16* __restrict__ w3b, const float* __restrict__ b3,
                 float* __restrict__ out) {
    __shared__ __align__(16) __hip_bfloat16 h1s[32 * H1S];
    __shared__ __align__(16) __hip_bfloat16 h2s[32 * H2S];

    const int tid  = threadIdx.x;
    const int wave = tid >> 6;
    const int lane = tid & 63;
    const int l15  = lane & 15;
    const int g    = lane >> 4;
    const int r0   = blockIdx.x * 32;
    const int rgA  = blockIdx.x * 2;

    // ---- GEMM1: h1 = relu(h0 @ w1 + b1), M=32 N=256 K=704 ----
    {
        const __hip_bfloat16* a0p = h0b + ((size_t)(rgA + 0) * 22) * 512 + l15 * 32 + g * 8;
        const __hip_bfloat16* a1p = h0b + ((size_t)(rgA + 1) * 22) * 512 + l15 * 32 + g * 8;
        const int nb = wave * 64;
        const __hip_bfloat16* bbase = w1b + ((size_t)(nb + l15) * 32 + g * 8);

        f32x4 acc[2][4];
        #pragma unroll
        for (int mt = 0; mt < 2; mt++)
            #pragma unroll
            for (int nt = 0; nt < 4; nt++)
                acc[mt][nt] = (f32x4){0.f, 0.f, 0.f, 0.f};

        bf16x8 bcur[4], acur[2];
        #pragma unroll
        for (int nt = 0; nt < 4; nt++)
            bcur[nt] = *(const bf16x8*)(bbase + nt * 512);
        acur[0] = *(const bf16x8*)(a0p);
        acur[1] = *(const bf16x8*)(a1p);

        for (int kc = 0; kc < KC1; kc++) {
            bf16x8 bnext[4], anext[2];
            if (kc + 1 < KC1) {
                const __hip_bfloat16* bp = bbase + (size_t)(kc + 1) * 8192;
                #pragma unroll
                for (int nt = 0; nt < 4; nt++)
                    bnext[nt] = *(const bf16x8*)(bp + nt * 512);
                anext[0] = *(const bf16x8*)(a0p + (size_t)(kc + 1) * 512);
                anext[1] = *(const bf16x8*)(a1p + (size_t)(kc + 1) * 512);
            }
            #pragma unroll
            for (int mt = 0; mt < 2; mt++)
                #pragma unroll
                for (int nt = 0; nt < 4; nt++)
                    acc[mt][nt] = __builtin_amdgcn_mfma_f32_16x16x32_bf16(
                        acur[mt], bcur[nt], acc[mt][nt], 0, 0, 0);
            if (kc + 1 < KC1) {
                #pragma unroll
                for (int nt = 0; nt < 4; nt++) bcur[nt] = bnext[nt];
                acur[0] = anext[0];
                acur[1] = anext[1];
            }
        }
        #pragma unroll
        for (int nt = 0; nt < 4; nt++) {
            const int n = nb + nt * 16 + l15;
            const float bias = b1[n];
            #pragma unroll
            for (int mt = 0; mt < 2; mt++) {
                #pragma unroll
                for (int q = 0; q < 4; q++) {
                    const int row = mt * 16 + g * 4 + q;
                    float v = acc[mt][nt][q] + bias;
                    h1s[row * H1S + n] = __float2bfloat16(fmaxf(v, 0.0f));
                }
            }
        }
    }
    __syncthreads();

    // ---- GEMM2: h2 = relu(h1 @ w2 + b2), M=32 N=128 K=256 ----
    {
        f32x4 acc[2][2];
        #pragma unroll
        for (int mt = 0; mt < 2; mt++)
            #pragma unroll
            for (int nt = 0; nt < 2; nt++)
                acc[mt][nt] = (f32x4){0.f, 0.f, 0.f, 0.f};
        const int nb = wave * 32;
        #pragma unroll
        for (int kc = 0; kc < KC2; kc++) {
            bf16x8 a[2], b[2];
            #pragma unroll
            for (int mt = 0; mt < 2; mt++)
                a[mt] = *(const bf16x8*)(h1s + (mt * 16 + l15) * H1S + kc * 32 + g * 8);
            #pragma unroll
            for (int nt = 0; nt < 2; nt++)
                b[nt] = *(const bf16x8*)(w2b + (((size_t)kc * 128 + nb + nt * 16 + l15) * 32 + g * 8));
            #pragma unroll
            for (int mt = 0; mt < 2; mt++)
                #pragma unroll
                for (int nt = 0; nt < 2; nt++)
                    acc[mt][nt] = __builtin_amdgcn_mfma_f32_16x16x32_bf16(
                        a[mt], b[nt], acc[mt][nt], 0, 0, 0);
        }
        #pragma unroll
        for (int nt = 0; nt < 2; nt++) {
            const int n = nb + nt * 16 + l15;
            const float bias = b2[n];
            #pragma unroll
            for (int mt = 0; mt < 2; mt++) {
                #pragma unroll
                for (int q = 0; q < 4; q++) {
                    const int row = mt * 16 + g * 4 + q;
                    float v = acc[mt][nt][q] + bias;
                    h2s[row * H2S + n] = __float2bfloat16(fmaxf(v, 0.0f));
                }
            }
        }
    }
    __syncthreads();

    // ---- GEMM3: out = h2 @ w3 + b3, M=32 N=16(10) K=128 ----
    if (wave < 2) {
        f32x4 acc3 = (f32x4){0.f, 0.f, 0.f, 0.f};
        #pragma unroll
        for (int kc = 0; kc < KC3; kc++) {
            bf16x8 a = *(const bf16x8*)(h2s + (wave * 16 + l15) * H2S + kc * 32 + g * 8);
            bf16x8 b = *(const bf16x8*)(w3b + (((size_t)kc * 16 + l15) * 32 + g * 8));
            acc3 = __builtin_amdgcn_mfma_f32_16x16x32_bf16(a, b, acc3, 0, 0, 0);
        }
        if (l15 < 10) {
            const float bias = b3[l15];
            #pragma unroll
            for (int q = 0; q < 4; q++) {
                const int row = wave * 16 + g * 4 + q;
                out[(size_t)(r0 + row) * 10 + l15] = acc3[q] + bias;
            }
        }
    }
}

extern "C" void kernel_launch(void* const* d_in, const int* in_sizes, int n_in,
                              void* d_out, int out_size, void* d_ws, size_t ws_size,
                              hipStream_t stream) {
    const float* x  = (const float*)d_in[0];
    const float* cw = (const float*)d_in[1];
    const float* w1 = (const float*)d_in[2];
    const float* b1 = (const float*)d_in[3];
    const float* w2 = (const float*)d_in[4];
    const float* b2 = (const float*)d_in[5];
    const float* w3 = (const float*)d_in[6];
    const float* b3 = (const float*)d_in[7];
    float* out = (float*)d_out;

    __hip_bfloat16* w1b = (__hip_bfloat16*)d_ws;
    __hip_bfloat16* w2b = w1b + W1B_ELEMS;
    __hip_bfloat16* w3b = w2b + W2B_ELEMS;
    __hip_bfloat16* h0b = (__hip_bfloat16*)((char*)d_ws + WPACK_BYTES);

    const int pack_total = W1B_ELEMS + W2B_ELEMS + W3B_ELEMS;  // 215040
    pack_weights<<<(pack_total + 255) / 256, 256, 0, stream>>>(w1, w2, w3, w1b, w2b, w3b);
    conv_kernel<<<B_ROWS / CG, 256, 0, stream>>>(x, cw, h0b);
    gemm_kernel<<<B_ROWS / 32, 256, 0, stream>>>(h0b, w1b, b1, w2b, b2, w3b, b3, out);
}